// Round 14
// baseline (838.497 us; speedup 1.0000x reference)
//
#include <hip/hip_runtime.h>

using u32 = unsigned int;
using u16 = unsigned short;

#define B_   4
#define S_   2048
#define D_   512
#define H_   8
#define DH_  64
#define FF_  2048
#define L_   6
#define NB_  32
#define KC_  8

typedef __attribute__((ext_vector_type(8))) __bf16 bf16x8;
typedef __attribute__((ext_vector_type(4))) float  f32x4;

struct Plan { unsigned char idx[NB_][KC_]; unsigned char cnt[NB_]; };

// Q prescale folded into QKV GEMM epilogue: 1/sqrt(64) * log2(e)  (base-2 softmax)
#define QSCALE 0.18033688011112042f

// ---------- helpers ----------
__device__ __forceinline__ u16 f2b(float f) {
  union { __bf16 b; u16 u; } x;
  x.b = (__bf16)f;            // hw v_cvt (RNE)
  return x.u;
}
__device__ __forceinline__ float b2f(u16 u) {
  union { u32 u; float f; } x;
  x.u = ((u32)u) << 16;
  return x.f;
}

// exact tanh-gelu via sigmoid identity: 0.5*(1+tanh(y)) == 1/(1+e^{-2y})
__device__ __forceinline__ float gelu_f(float x) {
  float y2 = 1.5957691216f * x + 0.0713548163f * x * x * x;  // 2*y
  return x / (1.0f + __expf(-y2));
}

// async global->LDS 16B per lane. dst = wave-uniform base; lane l lands at +l*16B.
typedef const __attribute__((address_space(1))) u32* gas_t;
typedef __attribute__((address_space(3))) u32* las_t;
__device__ __forceinline__ void glds16(const u16* g, u16* l) {
  __builtin_amdgcn_global_load_lds((gas_t)g, (las_t)l, 16, 0, 0);
}

// ---------- all weight transpose-converts in ONE dispatch ----------
// LN-fold: qkv weights scaled by ln1_s[k], w1 weights scaled by ln2_s[k].
__global__ __launch_bounds__(256)
void transpose_all(const float* __restrict__ wq, const float* __restrict__ wk,
                   const float* __restrict__ wv, const float* __restrict__ wo,
                   const float* __restrict__ w1, const float* __restrict__ w2,
                   const float* __restrict__ ln1_s, const float* __restrict__ ln2_s,
                   u16* __restrict__ wqkvT, u16* __restrict__ woT,
                   u16* __restrict__ w1T, u16* __restrict__ w2T) {
  __shared__ float tile[32][33];
  const int l = blockIdx.z;
  int idx = blockIdx.x;
  const float* src;
  u16* dst;
  int R, C, rowoff;
  size_t lstride;
  const float* gam = nullptr;
  if (idx < 768) {
    int w = idx >> 8; idx &= 255;
    src = (w == 0) ? wq : (w == 1) ? wk : wv;
    dst = wqkvT; R = 512; C = 512; lstride = (size_t)1536 * 512; rowoff = w * 512;
    gam = ln1_s + l * 512;
  } else if (idx < 1024) {
    idx -= 768;  src = wo; dst = woT; R = 512;  C = 512;  lstride = (size_t)512 * 512;  rowoff = 0;
  } else if (idx < 2048) {
    idx -= 1024; src = w1; dst = w1T; R = 512;  C = 2048; lstride = (size_t)2048 * 512; rowoff = 0;
    gam = ln2_s + l * 512;
  } else {
    idx -= 2048; src = w2; dst = w2T; R = 2048; C = 512;  lstride = (size_t)512 * 2048; rowoff = 0;
  }
  const int ntx = C >> 5;
  const int c0 = (idx % ntx) * 32, r0 = (idx / ntx) * 32;
  src += (size_t)l * R * C;
  dst += (size_t)l * lstride;
  const int tx = threadIdx.x, ty = threadIdx.y;
#pragma unroll
  for (int i = 0; i < 4; i++)
    tile[ty + i * 8][tx] = src[(size_t)(r0 + ty + i * 8) * C + c0 + tx];
  __syncthreads();
  const float gsc = gam ? gam[r0 + tx] : 1.0f;   // store col = k = r0+tx
#pragma unroll
  for (int i = 0; i < 4; i++)
    dst[(size_t)(rowoff + c0 + ty + i * 8) * R + r0 + tx] = f2b(tile[tx][ty + i * 8] * gsc);
}

// ---------- per-layer fold constants (COALESCED + ILP) ----------
__global__ __launch_bounds__(256)
void compute_uv(const float* __restrict__ wq, const float* __restrict__ wk,
                const float* __restrict__ wv, const float* __restrict__ w1,
                const float* __restrict__ ln1_b, const float* __restrict__ ln2_b,
                const u16* __restrict__ wqkvT, const u16* __restrict__ w1T,
                float* __restrict__ uvq, float* __restrict__ uv1) {
  __shared__ float su[4][64], sv[4][64];
  const int gid = blockIdx.x;
  const int l = gid / 56, seg = gid % 56;        // 56 segs of 64 cols = 3584
  const int t = threadIdx.x;
  const int lane = t & 63, wave = t >> 6;
  const int gn = seg * 64;                       // segment base (global n)

  const float* W; const float* beta; const u16* WT; float* uv; int C;
  if (gn < 1536) {
    int w = gn >> 9, nc0 = gn & 511;
    W = ((w == 0) ? wq : (w == 1) ? wk : wv) + (size_t)l * 512 * 512 + nc0;
    C = 512;
    beta = ln1_b + l * 512;
    WT = wqkvT + ((size_t)l * 1536 + gn) * 512;
    uv = uvq + ((size_t)l * 1536 + gn) * 2;
  } else {
    int nc0 = gn - 1536;
    W = w1 + (size_t)l * 512 * 2048 + nc0;
    C = 2048;
    beta = ln2_b + l * 512;
    WT = w1T + (size_t)nc0 * 512 + (size_t)l * 2048 * 512;
    uv = uv1 + ((size_t)l * 2048 + nc0) * 2;
  }

  float uu0 = 0.0f, uu1 = 0.0f;
#pragma unroll 16
  for (int i = 0; i < 128; i += 2) {
    const int k0 = wave + i * 4;
    const int k1 = wave + (i + 1) * 4;
    uu0 = fmaf(beta[k0], W[(size_t)k0 * C + lane], uu0);
    uu1 = fmaf(beta[k1], W[(size_t)k1 * C + lane], uu1);
  }
  float uu = uu0 + uu1;

  float vv = 0.0f;
  const uint4* wt4 = (const uint4*)(WT + (size_t)lane * 512 + wave * 128);
#pragma unroll
  for (int i = 0; i < 16; i++) {
    uint4 u4 = wt4[i];
    u32 us[4] = {u4.x, u4.y, u4.z, u4.w};
#pragma unroll
    for (int z = 0; z < 4; z++)
      vv += b2f((u16)(us[z] & 0xffffu)) + b2f((u16)(us[z] >> 16));
  }

  su[wave][lane] = uu;
  sv[wave][lane] = vv;
  __syncthreads();
  if (t < 64) {
    float u0 = su[0][t] + su[1][t] + su[2][t] + su[3][t];
    float v0 = sv[0][t] + sv[1][t] + sv[2][t] + sv[3][t];
    ((float2*)uv)[t] = make_float2(u0, v0);
  }
}

// ---------- embedding + sinusoidal pos; writes x bf16 + row stats ----------
__global__ __launch_bounds__(128)
void embed_stats(const int* __restrict__ tokens, const float* __restrict__ emb,
                 u16* __restrict__ x, float* __restrict__ pstats) {
  const int row = blockIdx.x;           // b*S + s
  const int s = row & (S_ - 1);
  const int t = threadIdx.x;
  const int tok = tokens[row];
  float4 v = ((const float4*)(emb + (size_t)tok * D_))[t];
  float va[4] = {v.x, v.y, v.z, v.w};
  const float cc = -2.0f * logf(10000.0f) / (float)D_;
  const float pos = (float)s;
#pragma unroll
  for (int j = 0; j < 4; j++) {
    int d = t * 4 + j;
    int i = d >> 1;
    float dv = expf(cc * (float)i);
    float ang = pos * dv;
    va[j] += (d & 1) ? cosf(ang) : sinf(ang);
  }
  ushort4 xb;
  xb.x = f2b(va[0]); xb.y = f2b(va[1]); xb.z = f2b(va[2]); xb.w = f2b(va[3]);
  ((ushort4*)x)[(size_t)row * (D_ / 4) + t] = xb;

  float sm = va[0] + va[1] + va[2] + va[3];
  float sq = va[0] * va[0] + va[1] * va[1] + va[2] * va[2] + va[3] * va[3];
#pragma unroll
  for (int d = 1; d < 64; d <<= 1) {
    sm += __shfl_xor(sm, d);
    sq += __shfl_xor(sq, d);
  }
  __shared__ float red[4];
  const int wv_ = t >> 6, lane = t & 63;
  if (lane == 0) { red[wv_ * 2] = sm; red[wv_ * 2 + 1] = sq; }
  __syncthreads();
  if (t < 8) {
    pstats[(size_t)row * 16 + t * 2]     = (t == 0) ? (red[0] + red[2]) : 0.0f;
    pstats[(size_t)row * 16 + t * 2 + 1] = (t == 0) ? (red[1] + red[3]) : 0.0f;
  }
}

// ---------- final layernorm from precomputed stats: x bf16 -> d_out f32 ----------
__global__ __launch_bounds__(128)
void ln_final(const u16* __restrict__ x, const float* __restrict__ pstats,
              const float* __restrict__ sc, const float* __restrict__ bi,
              float* __restrict__ outp) {
  const int row = blockIdx.x;
  const int t = threadIdx.x;
  float s = 0.0f, q = 0.0f;
#pragma unroll
  for (int i = 0; i < 8; i++) {
    s += pstats[(size_t)row * 16 + i * 2];
    q += pstats[(size_t)row * 16 + i * 2 + 1];
  }
  const float mean = s * (1.0f / (float)D_);
  const float inv  = rsqrtf(q * (1.0f / (float)D_) - mean * mean + 1e-6f);
  ushort4 xb = ((const ushort4*)(x + (size_t)row * D_))[t];
  float va[4] = {b2f(xb.x), b2f(xb.y), b2f(xb.z), b2f(xb.w)};
  const int d0 = t * 4;
  float o[4];
#pragma unroll
  for (int j = 0; j < 4; j++)
    o[j] = (va[j] - mean) * inv * sc[d0 + j] + bi[d0 + j];
  ((float4*)outp)[(size_t)row * (D_ / 4) + t] = make_float4(o[0], o[1], o[2], o[3]);
}

// ---------- TMxTN BK=64 GEMM, counted-vmcnt pipeline, multi-block/CU ----------
template <int MODE, bool VSPLIT, int TM, int TN, bool FOLD, bool STATS>
__global__ __launch_bounds__(TN * 2)
void gemm_pipe(const u16* __restrict__ A, const u16* __restrict__ BT,
               int Kk, int ostride, int ncols,
               u16* __restrict__ outb,
               const float* __restrict__ bias, const u16* __restrict__ resid,
               u16* __restrict__ vtout,
               const float* __restrict__ uv, const float* __restrict__ pstats_in,
               float* __restrict__ pstats_out) {
  constexpr int NW  = TN / 32;          // waves (2x(TN/64))
  constexpr int WC  = NW / 2;           // wave cols
  constexpr int MI  = TM / 32;          // per-wave 16-row frags
  constexpr int CHA = TM / (8 * NW);    // A-stage glds per wave
  constexpr int CHB = TN / (8 * NW);    // B-stage glds per wave
  constexpr int VM  = CHA + CHB;
  __shared__ u16 As[2][TM * 64];
  __shared__ u16 Bs[2][TN * 64];
  const int tid = threadIdx.x;
  const int wave = tid >> 6, lane = tid & 63;
  const int nwg = gridDim.x, cpx = nwg >> 3;
  const int bid = blockIdx.x;
  const int gid = (bid & 7) * cpx + (bid >> 3);
  const int row0 = (gid / ncols) * TM, col0 = (gid % ncols) * TN;
  const int wr = wave / WC, wc = wave % WC;
  const int l15 = lane & 15, l4 = lane >> 4;

  const u16* asrc[CHA];
  const u16* bsrc[CHB];
  int adst[CHA], bdst[CHB];
#pragma unroll
  for (int i = 0; i < CHA; i++) {
    int chunk = wave * (CHA * 64) + i * 64 + lane;
    int r = chunk >> 3, s = chunk & 7;
    asrc[i] = A + (size_t)(row0 + r) * Kk + ((s ^ (r & 7)) << 3);
    adst[i] = (wave * (CHA * 64) + i * 64) * 8;
  }
#pragma unroll
  for (int i = 0; i < CHB; i++) {
    int chunk = wave * (CHB * 64) + i * 64 + lane;
    int r = chunk >> 3, s = chunk & 7;
    bsrc[i] = BT + (size_t)(col0 + r) * Kk + ((s ^ (r & 7)) << 3);
    bdst[i] = (wave * (CHB * 64) + i * 64) * 8;
  }

  int aoff[MI], boff[4];
#pragma unroll
  for (int m = 0; m < MI; m++) aoff[m] = (wr * (MI * 16) + m * 16 + l15) * 64;
#pragma unroll
  for (int n = 0; n < 4; n++) boff[n] = (wc * 64 + n * 16 + l15) * 64;
  const int sk0 = ((l4)     ^ (l15 & 7)) << 3;
  const int sk1 = ((4 + l4) ^ (l15 & 7)) << 3;

  f32x4 acc[MI][4] = {};
  const int nk = Kk >> 6;

  auto stage = [&](int buf, int kt) {
    const int ko = kt << 6;
#pragma unroll
    for (int i = 0; i < CHA; i++) glds16(asrc[i] + ko, &As[buf][adst[i]]);
#pragma unroll
    for (int i = 0; i < CHB; i++) glds16(bsrc[i] + ko, &Bs[buf][bdst[i]]);
  };

  stage(0, 0);
  stage(1, 1);

  for (int kt = 0; kt < nk; ++kt) {
    const int cur = kt & 1;
    if (kt + 1 < nk) {
      if constexpr (VM == 8) { asm volatile("s_waitcnt vmcnt(8)" ::: "memory"); }
      else                   { asm volatile("s_waitcnt vmcnt(6)" ::: "memory"); }
    } else {
      asm volatile("s_waitcnt vmcnt(0)" ::: "memory");
    }
    __builtin_amdgcn_s_barrier();                 // B1: buf[cur] staged everywhere
    __builtin_amdgcn_sched_barrier(0);

    bf16x8 af0[MI], bf0[4];
#pragma unroll
    for (int m = 0; m < MI; m++) af0[m] = *(const bf16x8*)&As[cur][aoff[m] + sk0];
#pragma unroll
    for (int n = 0; n < 4; n++) bf0[n] = *(const bf16x8*)&Bs[cur][boff[n] + sk0];
    __builtin_amdgcn_s_setprio(1);
#pragma unroll
    for (int m = 0; m < MI; m++)
#pragma unroll
      for (int n = 0; n < 4; n++)
        acc[m][n] = __builtin_amdgcn_mfma_f32_16x16x32_bf16(af0[m], bf0[n], acc[m][n], 0, 0, 0);
    __builtin_amdgcn_s_setprio(0);

    bf16x8 af1[MI], bf1[4];
#pragma unroll
    for (int m = 0; m < MI; m++) af1[m] = *(const bf16x8*)&As[cur][aoff[m] + sk1];
#pragma unroll
    for (int n = 0; n < 4; n++) bf1[n] = *(const bf16x8*)&Bs[cur][boff[n] + sk1];
    asm volatile("s_waitcnt lgkmcnt(0)" ::: "memory");
    __builtin_amdgcn_sched_barrier(0);
    __builtin_amdgcn_s_barrier();                 // B2: all reads of buf[cur] done
    __builtin_amdgcn_sched_barrier(0);
    if (kt + 2 < nk) stage(cur, kt + 2);

    __builtin_amdgcn_s_setprio(1);
#pragma unroll
    for (int m = 0; m < MI; m++)
#pragma unroll
      for (int n = 0; n < 4; n++)
        acc[m][n] = __builtin_amdgcn_mfma_f32_16x16x32_bf16(af1[m], bf1[n], acc[m][n], 0, 0, 0);
    __builtin_amdgcn_s_setprio(0);
  }

  // ---- FOLD: cooperative per-row (mu, inv) from pstats_in (LDS-staged) ----
  float* sl = nullptr;
  float* mi = nullptr;
  if constexpr (FOLD) {
    __syncthreads();
    sl = (float*)&As[0][0];
    mi = sl + TM * 16;
    for (int i = tid; i < TM * 16; i += TN * 2)
      sl[i] = pstats_in[(size_t)row0 * 16 + i];
    __syncthreads();
    if (tid < TM) {
      float s = 0.0f, q = 0.0f;
#pragma unroll
      for (int t2 = 0; t2 < 8; t2++) { s += sl[tid * 16 + t2 * 2]; q += sl[tid * 16 + t2 * 2 + 1]; }
      const float mu = s * (1.0f / (float)D_);
      mi[tid * 2] = mu;
      mi[tid * 2 + 1] = rsqrtf(q * (1.0f / (float)D_) - mu * mu + 1e-6f);
    }
    __syncthreads();
  }

  float rs[MI][4], rq[MI][4];
  if constexpr (STATS) {
#pragma unroll
    for (int m = 0; m < MI; m++)
#pragma unroll
      for (int j = 0; j < 4; j++) { rs[m][j] = 0.0f; rq[m][j] = 0.0f; }
  }

#pragma unroll
  for (int m = 0; m < MI; m++) {
#pragma unroll
    for (int n = 0; n < 4; n++) {
      const int c = col0 + wc * 64 + n * 16 + l15;
      const int rb = row0 + wr * (MI * 16) + m * 16 + l4 * 4;
      float vals[4];
#pragma unroll
      for (int j = 0; j < 4; j++) {
        float v = acc[m][n][j];
        if constexpr (FOLD) {
          const int rl = wr * (MI * 16) + m * 16 + l4 * 4 + j;
          const float mu = mi[rl * 2], iv = mi[rl * 2 + 1];
          const float2 uvc = ((const float2*)uv)[c];
          v = v * iv + uvc.x - mu * iv * uvc.y;
        }
        vals[j] = v;
      }
      if (VSPLIT && c >= 1024) {
        u16 pk[4];
#pragma unroll
        for (int j = 0; j < 4; j++) pk[j] = f2b(vals[j]);
        *(uint2*)(vtout + (size_t)(c - 1024) * (B_ * S_) + rb) = *(const uint2*)pk;
      } else {
#pragma unroll
        for (int j = 0; j < 4; j++) {
          const size_t o = (size_t)(rb + j) * ostride + c;
          float v = vals[j];
          if (MODE == 0) {
            if (VSPLIT && c < 512) v *= QSCALE;
            outb[o] = f2b(v);
          } else if (MODE == 1) {
            v = v + b2f(resid[o]);
            outb[o] = f2b(v);
          } else if (MODE == 2) {
            outb[o] = f2b(gelu_f(v + bias[c]));
          } else {
            v = v + bias[c] + b2f(resid[o]);
            outb[o] = f2b(v);
          }
          if constexpr (STATS) { rs[m][j] += v; rq[m][j] += v * v; }
        }
      }
    }
  }

  if constexpr (STATS) {
#pragma unroll
    for (int m = 0; m < MI; m++)
#pragma unroll
      for (int j = 0; j < 4; j++) {
        float s = rs[m][j], q = rq[m][j];
#pragma unroll
        for (int d = 1; d < 16; d <<= 1) { s += __shfl_xor(s, d); q += __shfl_xor(q, d); }
        if (l15 == 0) {
          const int r = row0 + wr * (MI * 16) + m * 16 + l4 * 4 + j;
          const int slot = (col0 + wc * 64) >> 6;
          pstats_out[(size_t)r * 16 + slot * 2]     = s;
          pstats_out[(size_t)r * 16 + slot * 2 + 1] = q;
        }
      }
  }
}

// ---------- MFMA block-sparse attention, K/V^T double-buffered prefetch ----------
__global__ __launch_bounds__(256, 4)
void attn_mfma(const u16* __restrict__ qkv, const u16* __restrict__ vTg,
               const int* __restrict__ tokens, u16* __restrict__ outb, Plan plan) {
  __shared__ u16 ks[2][64 * 64];
  __shared__ u16 vt[2][64 * 64];
  __shared__ u16 ps[64 * 64];

  const int blk = blockIdx.x;
  const int h0 = blk & 7;
  const int n  = (blk >> 3) & 31;
  const int b  = blk >> 8;
  const int t  = threadIdx.x;
  const int wave = t >> 6, lane = t & 63;
  const int l15 = lane & 15, l4 = lane >> 4;
  const int ncnt = plan.cnt[n];
  const int qrow0 = b * S_ + n * 64;

  auto stage = [&](int bi, int c, int* tkd) {
    const int krow0 = b * S_ + c * 64;
#pragma unroll
    for (int i = 0; i < 2; i++) {
      int c0 = i * 256 + wave * 64;
      int cl = c0 + lane;
      int r = cl >> 3, s = cl & 7;
      int sw = (s ^ (r & 7)) << 3;
      glds16(qkv + (size_t)(krow0 + r) * 1024 + 512 + h0 * 64 + sw, &ks[bi][c0 * 8]);
      glds16(vTg + (size_t)(h0 * 64 + r) * (B_ * S_) + krow0 + sw, &vt[bi][c0 * 8]);
    }
#pragma unroll
    for (int nn = 0; nn < 4; nn++) tkd[nn] = tokens[krow0 + nn * 16 + l15];
  };

  bf16x8 qaf[2];
#pragma unroll
  for (int ks_ = 0; ks_ < 2; ks_++)
    qaf[ks_] = *(const bf16x8*)(qkv + (size_t)(qrow0 + wave * 16 + l15) * 1024 +
                                h0 * 64 + ks_ * 32 + l4 * 8);

  int tk[4], tn[4];
  stage(0, plan.idx[n][0], tk);

  f32x4 oacc[4] = {};
  float mrow[4], lrow[4];
#pragma unroll
  for (int j = 0; j < 4; j++) { mrow[j] = -3e38f; lrow[j] = 0.0f; }

  for (int kc = 0; kc < ncnt; kc++) {
    const int cur = kc & 1;
    __syncthreads();
    if (kc + 1 < ncnt) stage(cur ^ 1, plan.idx[n][kc + 1], tn);

    f32x4 sacc[4] = {};
    __builtin_amdgcn_s_setprio(1);
#pragma unroll
    for (int nn = 0; nn < 4; nn++) {
      int r = nn * 16 + l15;
#pragma unroll
      for (int ks_ = 0; ks_ < 2; ks_++) {
        bf16x8 kf = *(const bf16x8*)(&ks[cur][r * 64 + ((ks_ * 32 + l4 * 8) ^ ((r & 7) << 3))]);
        sacc[nn] = __builtin_amdgcn_mfma_f32_16x16x32_bf16(qaf[ks_], kf, sacc[nn], 0, 0, 0);
      }
    }
    __builtin_amdgcn_s_setprio(0);

    bool vld[4];
#pragma unroll
    for (int nn = 0; nn < 4; nn++) vld[nn] = tk[nn] > 0;

    float rmax[4];
#pragma unroll
    for (int j = 0; j < 4; j++) {
      float mj = -3e38f;
#pragma unroll
      for (int nn = 0; nn < 4; nn++)
        if (vld[nn]) mj = fmaxf(mj, sacc[nn][j]);
      rmax[j] = mj;
    }
#pragma unroll
    for (int d = 1; d < 16; d <<= 1) {
#pragma unroll
      for (int j = 0; j < 4; j++) rmax[j] = fmaxf(rmax[j], __shfl_xor(rmax[j], d));
    }
    // T13 defer-max: only rescale when a row max grows by >8 (log2 units).
    int chg = 0;
#pragma unroll
    for (int j = 0; j < 4; j++) chg |= (rmax[j] > mrow[j] + 8.0f);
    if (__ballot(chg)) {
#pragma unroll
      for (int j = 0; j < 4; j++) {
        float mn = fmaxf(mrow[j], rmax[j]);
        float alpha = exp2f(mrow[j] - mn);
        mrow[j] = mn;
        lrow[j] *= alpha;
#pragma unroll
        for (int n2 = 0; n2 < 4; n2++) oacc[n2][j] *= alpha;
      }
    }
    float p[4][4];
#pragma unroll
    for (int j = 0; j < 4; j++) {
      float psum = 0.0f;
#pragma unroll
      for (int nn = 0; nn < 4; nn++) {
        float pv = vld[nn] ? exp2f(sacc[nn][j] - mrow[j]) : 0.0f;
        p[nn][j] = pv;
        psum += pv;
      }
      lrow[j] += psum;
    }

#pragma unroll
    for (int nn = 0; nn < 4; nn++)
#pragma unroll
      for (int j = 0; j < 4; j++) {
        int q = wave * 16 + l4 * 4 + j;
        ps[q * 64 + ((nn * 16 + l15) ^ ((q & 7) << 3))] = f2b(p[nn][j]);
      }

    __builtin_amdgcn_s_setprio(1);
#pragma unroll
    for (int ks_ = 0; ks_ < 2; ks_++) {
      int r = wave * 16 + l15;
      bf16x8 paf = *(const bf16x8*)(ps + r * 64 + ((ks_ * 32 + l4 * 8) ^ ((r & 7) << 3)));
#pragma unroll
      for (int n2 = 0; n2 < 4; n2++) {
        int rv = n2 * 16 + l15;
        bf16x8 vf = *(const bf16x8*)(&vt[cur][rv * 64 + ((ks_ * 32 + l4 * 8) ^ ((rv & 7) << 3))]);
        oacc[n2] = __builtin_amdgcn_mfma_f32_16x16x32_bf16(paf, vf, oacc[n2], 0, 0, 0);
      }
    }
    __builtin_amdgcn_s_setprio(0);
#pragma unroll
    for (int nn = 0; nn < 4; nn++) tk[nn] = tn[nn];
  }

#pragma unroll
  for (int d = 1; d < 16; d <<= 1) {
#pragma unroll
    for (int j = 0; j < 4; j++) lrow[j] += __shfl_xor(lrow[j], d);
  }
#pragma unroll
  for (int j = 0; j < 4; j++) {
    const float inv = lrow[j] > 0.0f ? 1.0f / lrow[j] : 0.0f;
    const int q = n * 64 + wave * 16 + l4 * 4 + j;
#pragma unroll
    for (int n2 = 0; n2 < 4; n2++) {
      outb[(size_t)(b * S_ + q) * D_ + h0 * 64 + n2 * 16 + l15] = f2b(oacc[n2][j] * inv);
    }
  }
}

// ---------- host-side exact numpy RandomState(MT19937) plan ----------
namespace {
struct HostMT {
  u32 mt[624]; int mti;
  void seed(u32 s) {
    mt[0] = s;
    for (int i = 1; i < 624; i++)
      mt[i] = 1812433253u * (mt[i - 1] ^ (mt[i - 1] >> 30)) + (u32)i;
    mti = 624;
  }
  u32 next() {
    if (mti >= 624) {
      for (int k = 0; k < 624; k++) {
        u32 y = (mt[k] & 0x80000000u) | (mt[(k + 1) % 624] & 0x7fffffffu);
        mt[k] = mt[(k + 397) % 624] ^ (y >> 1) ^ ((y & 1u) ? 0x9908b0dfu : 0u);
      }
      mti = 0;
    }
    u32 y = mt[mti++];
    y ^= y >> 11;
    y ^= (y << 7)  & 0x9d2c5680u;
    y ^= (y << 15) & 0xefc60000u;
    y ^= y >> 18;
    return y;
  }
  u32 interval(u32 mx) {
    if (mx == 0u) return 0u;
    u32 mask = mx;
    mask |= mask >> 1; mask |= mask >> 2; mask |= mask >> 4;
    mask |= mask >> 8; mask |= mask >> 16;
    u32 v;
    while ((v = (next() & mask)) > mx) {}
    return v;
  }
};

void build_plan(int l, Plan* out) {
  HostMT rng;
  rng.seed((u32)l);
  for (int i = 0; i < NB_; i++) {
    bool fixedv[NB_] = {};
    fixedv[0] = true; fixedv[NB_ - 1] = true;
    for (int j = i - 1; j <= i + 1; j++)
      if (j >= 0 && j < NB_) fixedv[j] = true;
    int rest[NB_]; int nr = 0;
    for (int j = 0; j < NB_; j++) if (!fixedv[j]) rest[nr++] = j;
    int perm[NB_];
    for (int tt = 0; tt < nr; tt++) perm[tt] = tt;
    for (int tt = nr - 1; tt >= 1; tt--) {
      int j = (int)rng.interval((u32)tt);
      int tmp = perm[tt]; perm[tt] = perm[j]; perm[j] = tmp;
    }
    bool sel[NB_];
    for (int j = 0; j < NB_; j++) sel[j] = fixedv[j];
    for (int c = 0; c < 3; c++) sel[rest[perm[c]]] = true;
    int cnt = 0;
    for (int j = 0; j < NB_; j++)
      if (sel[j]) out->idx[i][cnt++] = (unsigned char)j;
    out->cnt[i] = (unsigned char)cnt;
    for (int c2 = cnt; c2 < KC_; c2++) out->idx[i][c2] = 0;
  }
}
}  // namespace

// ---------- host orchestration ----------
extern "C" void kernel_launch(void* const* d_in, const int* in_sizes, int n_in,
                              void* d_out, int out_size, void* d_ws, size_t ws_size,
                              hipStream_t stream) {
  (void)in_sizes; (void)n_in; (void)out_size; (void)ws_size;

  const int*   tokens = (const int*)d_in[0];
  const float* embed  = (const float*)d_in[1];
  const float* ln1_s  = (const float*)d_in[2];
  const float* ln1_b  = (const float*)d_in[3];
  const float* wq     = (const float*)d_in[4];
  const float* wk     = (const float*)d_in[5];
  const float* wv     = (const float*)d_in[6];
  const float* wo     = (const float*)d_in[7];
  const float* ln2_s  = (const float*)d_in[8];
  const float* ln2_b  = (const float*)d_in[9];
  const float* w1     = (const float*)d_in[10];
  const float* b1     = (const float*)d_in[11];
  const float* w2     = (const float*)d_in[12];
  const float* b2     = (const float*)d_in[13];
  const float* lnf_s  = (const float*)d_in[14];
  const float* lnf_b  = (const float*)d_in[15];

  char* wp = (char*)d_ws;
  auto take = [&](size_t bytes) {
    void* p = (void*)wp;
    wp += (bytes + 255) & ~(size_t)255;
    return p;
  };

  const int Mrows = B_ * S_;
  u16* wqkvT = (u16*)take((size_t)L_ * 1536 * D_ * 2);   // [L][1536][512] (gamma1-scaled)
  u16* woT   = (u16*)take((size_t)L_ * D_ * D_ * 2);     // [L][512][512]
  u16* w1T   = (u16*)take((size_t)L_ * FF_ * D_ * 2);    // [L][2048][512] (gamma2-scaled)
  u16* w2T   = (u16*)take((size_t)L_ * D_ * FF_ * 2);    // [L][512][2048]
  u16* x     = (u16*)take((size_t)Mrows * D_ * 2);       // residual stream, bf16
  u16* h     = (u16*)take((size_t)Mrows * D_ * 2);       // attn output
  float* pstats = (float*)take((size_t)Mrows * 16 * 4);  // [8192][8][2] partial LN stats
  float* uvq = (float*)take((size_t)L_ * 1536 * 2 * 4);  // per-col (u,v) for qkv
  float* uv1 = (float*)take((size_t)L_ * 2048 * 2 * 4);  // per-col (u,v) for w1
  u16* big   = (u16*)take((size_t)Mrows * FF_ * 2);      // {qkv+vT} | g, time-shared
  u16* qkv   = big;                                      // [8192][1024] q|k
  u16* vT    = big + (size_t)Mrows * 1024;               // [512][8192]
  u16* g     = big;

  Plan plans[L_];
  for (int l = 0; l < L_; l++) build_plan(l, &plans[l]);

  const size_t qkvL = (size_t)1536 * D_;

  transpose_all<<<dim3(3072, 1, L_), dim3(32, 8), 0, stream>>>(
      wq, wk, wv, wo, w1, w2, ln1_s, ln2_s, wqkvT, woT, w1T, w2T);
  compute_uv<<<L_ * 56, 256, 0, stream>>>(
      wq, wk, wv, w1, ln1_b, ln2_b, wqkvT, w1T, uvq, uv1);
  embed_stats<<<Mrows, 128, 0, stream>>>(tokens, embed, x, pstats);

  for (int l = 0; l < L_; l++) {
    gemm_pipe<0, true, 128, 128, true, false><<<768, 256, 0, stream>>>(
        x, wqkvT + (size_t)l * qkvL, D_, 1024, 12, qkv, nullptr, nullptr, vT,
        uvq + (size_t)l * 1536 * 2, pstats, nullptr);
    attn_mfma<<<B_ * NB_ * H_, 256, 0, stream>>>(qkv, vT, tokens, h, plans[l]);
    gemm_pipe<1, false, 64, 128, false, true><<<512, 256, 0, stream>>>(
        h, woT + (size_t)l * D_ * D_, D_, D_, 4, x, nullptr, x, nullptr,
        nullptr, nullptr, pstats);
    gemm_pipe<2, false, 128, 128, true, false><<<1024, 256, 0, stream>>>(
        x, w1T + (size_t)l * FF_ * D_, D_, FF_, 16, g, b1 + l * FF_, nullptr, nullptr,
        uv1 + (size_t)l * 2048 * 2, pstats, nullptr);
    gemm_pipe<3, false, 64, 128, false, true><<<512, 256, 0, stream>>>(
        g, w2T + (size_t)l * D_ * FF_, FF_, D_, 4, x, b2 + l * D_, x, nullptr,
        nullptr, nullptr, pstats);
  }
  ln_final<<<Mrows, 128, 0, stream>>>(x, pstats, lnf_s, lnf_b, (float*)d_out);
}

// Round 15
// 834.756 us; speedup vs baseline: 1.0045x; 1.0045x over previous
//
#include <hip/hip_runtime.h>

using u32 = unsigned int;
using u16 = unsigned short;

#define B_   4
#define S_   2048
#define D_   512
#define H_   8
#define DH_  64
#define FF_  2048
#define L_   6
#define NB_  32
#define KC_  8

typedef __attribute__((ext_vector_type(8))) __bf16 bf16x8;
typedef __attribute__((ext_vector_type(4))) float  f32x4;

struct Plan { unsigned char idx[NB_][KC_]; unsigned char cnt[NB_]; };

// Q prescale folded into QKV GEMM epilogue: 1/sqrt(64) * log2(e)  (base-2 softmax)
#define QSCALE 0.18033688011112042f

// ---------- helpers ----------
__device__ __forceinline__ u16 f2b(float f) {
  union { __bf16 b; u16 u; } x;
  x.b = (__bf16)f;            // hw v_cvt (RNE)
  return x.u;
}
__device__ __forceinline__ float b2f(u16 u) {
  union { u32 u; float f; } x;
  x.u = ((u32)u) << 16;
  return x.f;
}

// exact tanh-gelu via sigmoid identity: 0.5*(1+tanh(y)) == 1/(1+e^{-2y})
__device__ __forceinline__ float gelu_f(float x) {
  float y2 = 1.5957691216f * x + 0.0713548163f * x * x * x;  // 2*y
  return x / (1.0f + __expf(-y2));
}

// async global->LDS 16B per lane. dst = wave-uniform base; lane l lands at +l*16B.
typedef const __attribute__((address_space(1))) u32* gas_t;
typedef __attribute__((address_space(3))) u32* las_t;
__device__ __forceinline__ void glds16(const u16* g, u16* l) {
  __builtin_amdgcn_global_load_lds((gas_t)g, (las_t)l, 16, 0, 0);
}

// ---------- all weight transpose-converts in ONE dispatch ----------
// LN-fold: qkv weights scaled by ln1_s[k], w1 weights scaled by ln2_s[k].
__global__ __launch_bounds__(256)
void transpose_all(const float* __restrict__ wq, const float* __restrict__ wk,
                   const float* __restrict__ wv, const float* __restrict__ wo,
                   const float* __restrict__ w1, const float* __restrict__ w2,
                   const float* __restrict__ ln1_s, const float* __restrict__ ln2_s,
                   u16* __restrict__ wqkvT, u16* __restrict__ woT,
                   u16* __restrict__ w1T, u16* __restrict__ w2T) {
  __shared__ float tile[32][33];
  const int l = blockIdx.z;
  int idx = blockIdx.x;
  const float* src;
  u16* dst;
  int R, C, rowoff;
  size_t lstride;
  const float* gam = nullptr;
  if (idx < 768) {
    int w = idx >> 8; idx &= 255;
    src = (w == 0) ? wq : (w == 1) ? wk : wv;
    dst = wqkvT; R = 512; C = 512; lstride = (size_t)1536 * 512; rowoff = w * 512;
    gam = ln1_s + l * 512;
  } else if (idx < 1024) {
    idx -= 768;  src = wo; dst = woT; R = 512;  C = 512;  lstride = (size_t)512 * 512;  rowoff = 0;
  } else if (idx < 2048) {
    idx -= 1024; src = w1; dst = w1T; R = 512;  C = 2048; lstride = (size_t)2048 * 512; rowoff = 0;
    gam = ln2_s + l * 512;
  } else {
    idx -= 2048; src = w2; dst = w2T; R = 2048; C = 512;  lstride = (size_t)512 * 2048; rowoff = 0;
  }
  const int ntx = C >> 5;
  const int c0 = (idx % ntx) * 32, r0 = (idx / ntx) * 32;
  src += (size_t)l * R * C;
  dst += (size_t)l * lstride;
  const int tx = threadIdx.x, ty = threadIdx.y;
#pragma unroll
  for (int i = 0; i < 4; i++)
    tile[ty + i * 8][tx] = src[(size_t)(r0 + ty + i * 8) * C + c0 + tx];
  __syncthreads();
  const float gsc = gam ? gam[r0 + tx] : 1.0f;   // store col = k = r0+tx
#pragma unroll
  for (int i = 0; i < 4; i++)
    dst[(size_t)(rowoff + c0 + ty + i * 8) * R + r0 + tx] = f2b(tile[tx][ty + i * 8] * gsc);
}

// ---------- per-layer fold constants (COALESCED + ILP) ----------
__global__ __launch_bounds__(256)
void compute_uv(const float* __restrict__ wq, const float* __restrict__ wk,
                const float* __restrict__ wv, const float* __restrict__ w1,
                const float* __restrict__ ln1_b, const float* __restrict__ ln2_b,
                const u16* __restrict__ wqkvT, const u16* __restrict__ w1T,
                float* __restrict__ uvq, float* __restrict__ uv1) {
  __shared__ float su[4][64], sv[4][64];
  const int gid = blockIdx.x;
  const int l = gid / 56, seg = gid % 56;        // 56 segs of 64 cols = 3584
  const int t = threadIdx.x;
  const int lane = t & 63, wave = t >> 6;
  const int gn = seg * 64;                       // segment base (global n)

  const float* W; const float* beta; const u16* WT; float* uv; int C;
  if (gn < 1536) {
    int w = gn >> 9, nc0 = gn & 511;
    W = ((w == 0) ? wq : (w == 1) ? wk : wv) + (size_t)l * 512 * 512 + nc0;
    C = 512;
    beta = ln1_b + l * 512;
    WT = wqkvT + ((size_t)l * 1536 + gn) * 512;
    uv = uvq + ((size_t)l * 1536 + gn) * 2;
  } else {
    int nc0 = gn - 1536;
    W = w1 + (size_t)l * 512 * 2048 + nc0;
    C = 2048;
    beta = ln2_b + l * 512;
    WT = w1T + (size_t)nc0 * 512 + (size_t)l * 2048 * 512;
    uv = uv1 + ((size_t)l * 2048 + nc0) * 2;
  }

  float uu0 = 0.0f, uu1 = 0.0f;
#pragma unroll 16
  for (int i = 0; i < 128; i += 2) {
    const int k0 = wave + i * 4;
    const int k1 = wave + (i + 1) * 4;
    uu0 = fmaf(beta[k0], W[(size_t)k0 * C + lane], uu0);
    uu1 = fmaf(beta[k1], W[(size_t)k1 * C + lane], uu1);
  }
  float uu = uu0 + uu1;

  float vv = 0.0f;
  const uint4* wt4 = (const uint4*)(WT + (size_t)lane * 512 + wave * 128);
#pragma unroll
  for (int i = 0; i < 16; i++) {
    uint4 u4 = wt4[i];
    u32 us[4] = {u4.x, u4.y, u4.z, u4.w};
#pragma unroll
    for (int z = 0; z < 4; z++)
      vv += b2f((u16)(us[z] & 0xffffu)) + b2f((u16)(us[z] >> 16));
  }

  su[wave][lane] = uu;
  sv[wave][lane] = vv;
  __syncthreads();
  if (t < 64) {
    float u0 = su[0][t] + su[1][t] + su[2][t] + su[3][t];
    float v0 = sv[0][t] + sv[1][t] + sv[2][t] + sv[3][t];
    ((float2*)uv)[t] = make_float2(u0, v0);
  }
}

// ---------- embedding + sinusoidal pos; writes x bf16 + row stats ----------
__global__ __launch_bounds__(128)
void embed_stats(const int* __restrict__ tokens, const float* __restrict__ emb,
                 u16* __restrict__ x, float* __restrict__ pstats) {
  const int row = blockIdx.x;           // b*S + s
  const int s = row & (S_ - 1);
  const int t = threadIdx.x;
  const int tok = tokens[row];
  float4 v = ((const float4*)(emb + (size_t)tok * D_))[t];
  float va[4] = {v.x, v.y, v.z, v.w};
  const float cc = -2.0f * logf(10000.0f) / (float)D_;
  const float pos = (float)s;
#pragma unroll
  for (int j = 0; j < 4; j++) {
    int d = t * 4 + j;
    int i = d >> 1;
    float dv = expf(cc * (float)i);
    float ang = pos * dv;
    va[j] += (d & 1) ? cosf(ang) : sinf(ang);
  }
  ushort4 xb;
  xb.x = f2b(va[0]); xb.y = f2b(va[1]); xb.z = f2b(va[2]); xb.w = f2b(va[3]);
  ((ushort4*)x)[(size_t)row * (D_ / 4) + t] = xb;

  float sm = va[0] + va[1] + va[2] + va[3];
  float sq = va[0] * va[0] + va[1] * va[1] + va[2] * va[2] + va[3] * va[3];
#pragma unroll
  for (int d = 1; d < 64; d <<= 1) {
    sm += __shfl_xor(sm, d);
    sq += __shfl_xor(sq, d);
  }
  __shared__ float red[4];
  const int wv_ = t >> 6, lane = t & 63;
  if (lane == 0) { red[wv_ * 2] = sm; red[wv_ * 2 + 1] = sq; }
  __syncthreads();
  if (t < 8) {
    pstats[(size_t)row * 16 + t * 2]     = (t == 0) ? (red[0] + red[2]) : 0.0f;
    pstats[(size_t)row * 16 + t * 2 + 1] = (t == 0) ? (red[1] + red[3]) : 0.0f;
  }
}

// ---------- final layernorm from precomputed stats: x bf16 -> d_out f32 ----------
__global__ __launch_bounds__(128)
void ln_final(const u16* __restrict__ x, const float* __restrict__ pstats,
              const float* __restrict__ sc, const float* __restrict__ bi,
              float* __restrict__ outp) {
  const int row = blockIdx.x;
  const int t = threadIdx.x;
  float s = 0.0f, q = 0.0f;
#pragma unroll
  for (int i = 0; i < 8; i++) {
    s += pstats[(size_t)row * 16 + i * 2];
    q += pstats[(size_t)row * 16 + i * 2 + 1];
  }
  const float mean = s * (1.0f / (float)D_);
  const float inv  = rsqrtf(q * (1.0f / (float)D_) - mean * mean + 1e-6f);
  ushort4 xb = ((const ushort4*)(x + (size_t)row * D_))[t];
  float va[4] = {b2f(xb.x), b2f(xb.y), b2f(xb.z), b2f(xb.w)};
  const int d0 = t * 4;
  float o[4];
#pragma unroll
  for (int j = 0; j < 4; j++)
    o[j] = (va[j] - mean) * inv * sc[d0 + j] + bi[d0 + j];
  ((float4*)outp)[(size_t)row * (D_ / 4) + t] = make_float4(o[0], o[1], o[2], o[3]);
}

// ---------- TMxTN BK=64 GEMM, counted-vmcnt pipeline, multi-block/CU ----------
// MODE 0: out bf16 (QSCALE on q-cols if VSPLIT; vT split for cols>=1024)
// MODE 1: out bf16 = acc + resid(bf16)         [+STATS: emit row partial stats]
// MODE 2: out bf16 = gelu(acc + bias)          [FOLD applies LN before bias]
// MODE 3: out bf16 = acc + bias + resid(bf16)  [+STATS]
// FOLD: A is raw x; BT is gamma-scaled; epilogue v' = v*inv + u[c] - mu*inv*vv[c]
//       with per-row (mu,inv) from pstats_in (8 partial slots per row).
template <int MODE, bool VSPLIT, int TM, int TN, bool FOLD, bool STATS>
__global__ __launch_bounds__(TN * 2)
void gemm_pipe(const u16* __restrict__ A, const u16* __restrict__ BT,
               int Kk, int ostride, int ncols,
               u16* __restrict__ outb,
               const float* __restrict__ bias, const u16* __restrict__ resid,
               u16* __restrict__ vtout,
               const float* __restrict__ uv, const float* __restrict__ pstats_in,
               float* __restrict__ pstats_out) {
  constexpr int NW  = TN / 32;          // waves (2x(TN/64))
  constexpr int WC  = NW / 2;           // wave cols
  constexpr int MI  = TM / 32;          // per-wave 16-row frags
  constexpr int CHA = TM / (8 * NW);    // A-stage glds per wave
  constexpr int CHB = TN / (8 * NW);    // B-stage glds per wave
  constexpr int VM  = CHA + CHB;
  __shared__ u16 As[2][TM * 64];
  __shared__ u16 Bs[2][TN * 64];
  const int tid = threadIdx.x;
  const int wave = tid >> 6, lane = tid & 63;
  const int nwg = gridDim.x, cpx = nwg >> 3;
  const int bid = blockIdx.x;
  const int gid = (bid & 7) * cpx + (bid >> 3);
  const int row0 = (gid / ncols) * TM, col0 = (gid % ncols) * TN;
  const int wr = wave / WC, wc = wave % WC;
  const int l15 = lane & 15, l4 = lane >> 4;

  const u16* asrc[CHA];
  const u16* bsrc[CHB];
  int adst[CHA], bdst[CHB];
#pragma unroll
  for (int i = 0; i < CHA; i++) {
    int chunk = wave * (CHA * 64) + i * 64 + lane;
    int r = chunk >> 3, s = chunk & 7;
    asrc[i] = A + (size_t)(row0 + r) * Kk + ((s ^ (r & 7)) << 3);
    adst[i] = (wave * (CHA * 64) + i * 64) * 8;
  }
#pragma unroll
  for (int i = 0; i < CHB; i++) {
    int chunk = wave * (CHB * 64) + i * 64 + lane;
    int r = chunk >> 3, s = chunk & 7;
    bsrc[i] = BT + (size_t)(col0 + r) * Kk + ((s ^ (r & 7)) << 3);
    bdst[i] = (wave * (CHB * 64) + i * 64) * 8;
  }

  int aoff[MI], boff[4];
#pragma unroll
  for (int m = 0; m < MI; m++) aoff[m] = (wr * (MI * 16) + m * 16 + l15) * 64;
#pragma unroll
  for (int n = 0; n < 4; n++) boff[n] = (wc * 64 + n * 16 + l15) * 64;
  const int sk0 = ((l4)     ^ (l15 & 7)) << 3;
  const int sk1 = ((4 + l4) ^ (l15 & 7)) << 3;

  f32x4 acc[MI][4] = {};
  const int nk = Kk >> 6;

  auto stage = [&](int buf, int kt) {
    const int ko = kt << 6;
#pragma unroll
    for (int i = 0; i < CHA; i++) glds16(asrc[i] + ko, &As[buf][adst[i]]);
#pragma unroll
    for (int i = 0; i < CHB; i++) glds16(bsrc[i] + ko, &Bs[buf][bdst[i]]);
  };

  stage(0, 0);
  stage(1, 1);

  for (int kt = 0; kt < nk; ++kt) {
    const int cur = kt & 1;
    if (kt + 1 < nk) {
      if constexpr (VM == 8) { asm volatile("s_waitcnt vmcnt(8)" ::: "memory"); }
      else                   { asm volatile("s_waitcnt vmcnt(6)" ::: "memory"); }
    } else {
      asm volatile("s_waitcnt vmcnt(0)" ::: "memory");
    }
    __builtin_amdgcn_s_barrier();                 // B1: buf[cur] staged everywhere
    __builtin_amdgcn_sched_barrier(0);

    bf16x8 af0[MI], bf0[4];
#pragma unroll
    for (int m = 0; m < MI; m++) af0[m] = *(const bf16x8*)&As[cur][aoff[m] + sk0];
#pragma unroll
    for (int n = 0; n < 4; n++) bf0[n] = *(const bf16x8*)&Bs[cur][boff[n] + sk0];
#pragma unroll
    for (int m = 0; m < MI; m++)
#pragma unroll
      for (int n = 0; n < 4; n++)
        acc[m][n] = __builtin_amdgcn_mfma_f32_16x16x32_bf16(af0[m], bf0[n], acc[m][n], 0, 0, 0);

    bf16x8 af1[MI], bf1[4];
#pragma unroll
    for (int m = 0; m < MI; m++) af1[m] = *(const bf16x8*)&As[cur][aoff[m] + sk1];
#pragma unroll
    for (int n = 0; n < 4; n++) bf1[n] = *(const bf16x8*)&Bs[cur][boff[n] + sk1];
    asm volatile("s_waitcnt lgkmcnt(0)" ::: "memory");
    __builtin_amdgcn_sched_barrier(0);
    __builtin_amdgcn_s_barrier();                 // B2: all reads of buf[cur] done
    __builtin_amdgcn_sched_barrier(0);
    if (kt + 2 < nk) stage(cur, kt + 2);

    __builtin_amdgcn_s_setprio(1);
#pragma unroll
    for (int m = 0; m < MI; m++)
#pragma unroll
      for (int n = 0; n < 4; n++)
        acc[m][n] = __builtin_amdgcn_mfma_f32_16x16x32_bf16(af1[m], bf1[n], acc[m][n], 0, 0, 0);
    __builtin_amdgcn_s_setprio(0);
  }

  // ---- FOLD: cooperative per-row (mu, inv) from pstats_in (LDS-staged) ----
  float* sl = nullptr;
  float* mi = nullptr;
  if constexpr (FOLD) {
    __syncthreads();
    sl = (float*)&As[0][0];
    mi = sl + TM * 16;
    for (int i = tid; i < TM * 16; i += TN * 2)
      sl[i] = pstats_in[(size_t)row0 * 16 + i];
    __syncthreads();
    if (tid < TM) {
      float s = 0.0f, q = 0.0f;
#pragma unroll
      for (int t2 = 0; t2 < 8; t2++) { s += sl[tid * 16 + t2 * 2]; q += sl[tid * 16 + t2 * 2 + 1]; }
      const float mu = s * (1.0f / (float)D_);
      mi[tid * 2] = mu;
      mi[tid * 2 + 1] = rsqrtf(q * (1.0f / (float)D_) - mu * mu + 1e-6f);
    }
    __syncthreads();
  }

  float rs[MI][4], rq[MI][4];
  if constexpr (STATS) {
#pragma unroll
    for (int m = 0; m < MI; m++)
#pragma unroll
      for (int j = 0; j < 4; j++) { rs[m][j] = 0.0f; rq[m][j] = 0.0f; }
  }

#pragma unroll
  for (int m = 0; m < MI; m++) {
#pragma unroll
    for (int n = 0; n < 4; n++) {
      const int c = col0 + wc * 64 + n * 16 + l15;
      const int rb = row0 + wr * (MI * 16) + m * 16 + l4 * 4;
      float vals[4];
#pragma unroll
      for (int j = 0; j < 4; j++) {
        float v = acc[m][n][j];
        if constexpr (FOLD) {
          const int rl = wr * (MI * 16) + m * 16 + l4 * 4 + j;
          const float mu = mi[rl * 2], iv = mi[rl * 2 + 1];
          const float2 uvc = ((const float2*)uv)[c];
          v = v * iv + uvc.x - mu * iv * uvc.y;
        }
        vals[j] = v;
      }
      if (VSPLIT && c >= 1024) {
        u16 pk[4];
#pragma unroll
        for (int j = 0; j < 4; j++) pk[j] = f2b(vals[j]);
        *(uint2*)(vtout + (size_t)(c - 1024) * (B_ * S_) + rb) = *(const uint2*)pk;
      } else {
#pragma unroll
        for (int j = 0; j < 4; j++) {
          const size_t o = (size_t)(rb + j) * ostride + c;
          float v = vals[j];
          if (MODE == 0) {
            if (VSPLIT && c < 512) v *= QSCALE;
            outb[o] = f2b(v);
          } else if (MODE == 1) {
            v = v + b2f(resid[o]);
            outb[o] = f2b(v);
          } else if (MODE == 2) {
            outb[o] = f2b(gelu_f(v + bias[c]));
          } else {
            v = v + bias[c] + b2f(resid[o]);
            outb[o] = f2b(v);
          }
          if constexpr (STATS) { rs[m][j] += v; rq[m][j] += v * v; }
        }
      }
    }
  }

  if constexpr (STATS) {
#pragma unroll
    for (int m = 0; m < MI; m++)
#pragma unroll
      for (int j = 0; j < 4; j++) {
        float s = rs[m][j], q = rq[m][j];
#pragma unroll
        for (int d = 1; d < 16; d <<= 1) { s += __shfl_xor(s, d); q += __shfl_xor(q, d); }
        if (l15 == 0) {
          const int r = row0 + wr * (MI * 16) + m * 16 + l4 * 4 + j;
          const int slot = (col0 + wc * 64) >> 6;
          pstats_out[(size_t)r * 16 + slot * 2]     = s;
          pstats_out[(size_t)r * 16 + slot * 2 + 1] = q;
        }
      }
  }
}

// ---------- MFMA block-sparse attention, K/V^T double-buffered prefetch ----------
__global__ __launch_bounds__(256, 4)
void attn_mfma(const u16* __restrict__ qkv, const u16* __restrict__ vTg,
               const int* __restrict__ tokens, u16* __restrict__ outb, Plan plan) {
  __shared__ u16 ks[2][64 * 64];
  __shared__ u16 vt[2][64 * 64];
  __shared__ u16 ps[64 * 64];

  const int blk = blockIdx.x;
  const int h0 = blk & 7;
  const int n  = (blk >> 3) & 31;
  const int b  = blk >> 8;
  const int t  = threadIdx.x;
  const int wave = t >> 6, lane = t & 63;
  const int l15 = lane & 15, l4 = lane >> 4;
  const int ncnt = plan.cnt[n];
  const int qrow0 = b * S_ + n * 64;

  auto stage = [&](int bi, int c, int* tkd) {
    const int krow0 = b * S_ + c * 64;
#pragma unroll
    for (int i = 0; i < 2; i++) {
      int c0 = i * 256 + wave * 64;
      int cl = c0 + lane;
      int r = cl >> 3, s = cl & 7;
      int sw = (s ^ (r & 7)) << 3;
      glds16(qkv + (size_t)(krow0 + r) * 1024 + 512 + h0 * 64 + sw, &ks[bi][c0 * 8]);
      glds16(vTg + (size_t)(h0 * 64 + r) * (B_ * S_) + krow0 + sw, &vt[bi][c0 * 8]);
    }
#pragma unroll
    for (int nn = 0; nn < 4; nn++) tkd[nn] = tokens[krow0 + nn * 16 + l15];
  };

  bf16x8 qaf[2];
#pragma unroll
  for (int ks_ = 0; ks_ < 2; ks_++)
    qaf[ks_] = *(const bf16x8*)(qkv + (size_t)(qrow0 + wave * 16 + l15) * 1024 +
                                h0 * 64 + ks_ * 32 + l4 * 8);

  int tk[4], tn[4];
  stage(0, plan.idx[n][0], tk);

  f32x4 oacc[4] = {};
  float mrow[4], lrow[4];
#pragma unroll
  for (int j = 0; j < 4; j++) { mrow[j] = -3e38f; lrow[j] = 0.0f; }

  for (int kc = 0; kc < ncnt; kc++) {
    const int cur = kc & 1;
    __syncthreads();
    if (kc + 1 < ncnt) stage(cur ^ 1, plan.idx[n][kc + 1], tn);

    f32x4 sacc[4] = {};
#pragma unroll
    for (int nn = 0; nn < 4; nn++) {
      int r = nn * 16 + l15;
#pragma unroll
      for (int ks_ = 0; ks_ < 2; ks_++) {
        bf16x8 kf = *(const bf16x8*)(&ks[cur][r * 64 + ((ks_ * 32 + l4 * 8) ^ ((r & 7) << 3))]);
        sacc[nn] = __builtin_amdgcn_mfma_f32_16x16x32_bf16(qaf[ks_], kf, sacc[nn], 0, 0, 0);
      }
    }

    bool vld[4];
#pragma unroll
    for (int nn = 0; nn < 4; nn++) vld[nn] = tk[nn] > 0;

    float rmax[4];
#pragma unroll
    for (int j = 0; j < 4; j++) {
      float mj = -3e38f;
#pragma unroll
      for (int nn = 0; nn < 4; nn++)
        if (vld[nn]) mj = fmaxf(mj, sacc[nn][j]);
      rmax[j] = mj;
    }
#pragma unroll
    for (int d = 1; d < 16; d <<= 1) {
#pragma unroll
      for (int j = 0; j < 4; j++) rmax[j] = fmaxf(rmax[j], __shfl_xor(rmax[j], d));
    }
    // T13 defer-max: only rescale when a row max grows by >8 (log2 units).
    int chg = 0;
#pragma unroll
    for (int j = 0; j < 4; j++) chg |= (rmax[j] > mrow[j] + 8.0f);
    if (__ballot(chg)) {
#pragma unroll
      for (int j = 0; j < 4; j++) {
        float mn = fmaxf(mrow[j], rmax[j]);
        float alpha = exp2f(mrow[j] - mn);
        mrow[j] = mn;
        lrow[j] *= alpha;
#pragma unroll
        for (int n2 = 0; n2 < 4; n2++) oacc[n2][j] *= alpha;
      }
    }
    float p[4][4];
#pragma unroll
    for (int j = 0; j < 4; j++) {
      float psum = 0.0f;
#pragma unroll
      for (int nn = 0; nn < 4; nn++) {
        float pv = vld[nn] ? exp2f(sacc[nn][j] - mrow[j]) : 0.0f;
        p[nn][j] = pv;
        psum += pv;
      }
      lrow[j] += psum;
    }

#pragma unroll
    for (int nn = 0; nn < 4; nn++)
#pragma unroll
      for (int j = 0; j < 4; j++) {
        int q = wave * 16 + l4 * 4 + j;
        ps[q * 64 + ((nn * 16 + l15) ^ ((q & 7) << 3))] = f2b(p[nn][j]);
      }

#pragma unroll
    for (int ks_ = 0; ks_ < 2; ks_++) {
      int r = wave * 16 + l15;
      bf16x8 paf = *(const bf16x8*)(ps + r * 64 + ((ks_ * 32 + l4 * 8) ^ ((r & 7) << 3)));
#pragma unroll
      for (int n2 = 0; n2 < 4; n2++) {
        int rv = n2 * 16 + l15;
        bf16x8 vf = *(const bf16x8*)(&vt[cur][rv * 64 + ((ks_ * 32 + l4 * 8) ^ ((rv & 7) << 3))]);
        oacc[n2] = __builtin_amdgcn_mfma_f32_16x16x32_bf16(paf, vf, oacc[n2], 0, 0, 0);
      }
    }
#pragma unroll
    for (int nn = 0; nn < 4; nn++) tk[nn] = tn[nn];
  }

#pragma unroll
  for (int d = 1; d < 16; d <<= 1) {
#pragma unroll
    for (int j = 0; j < 4; j++) lrow[j] += __shfl_xor(lrow[j], d);
  }
#pragma unroll
  for (int j = 0; j < 4; j++) {
    const float inv = lrow[j] > 0.0f ? 1.0f / lrow[j] : 0.0f;
    const int q = n * 64 + wave * 16 + l4 * 4 + j;
#pragma unroll
    for (int n2 = 0; n2 < 4; n2++) {
      outb[(size_t)(b * S_ + q) * D_ + h0 * 64 + n2 * 16 + l15] = f2b(oacc[n2][j] * inv);
    }
  }
}

// ---------- host-side exact numpy RandomState(MT19937) plan ----------
namespace {
struct HostMT {
  u32 mt[624]; int mti;
  void seed(u32 s) {
    mt[0] = s;
    for (int i = 1; i < 624; i++)
      mt[i] = 1812433253u * (mt[i - 1] ^ (mt[i - 1] >> 30)) + (u32)i;
    mti = 624;
  }
  u32 next() {
    if (mti >= 624) {
      for (int k = 0; k < 624; k++) {
        u32 y = (mt[k] & 0x80000000u) | (mt[(k + 1) % 624] & 0x7fffffffu);
        mt[k] = mt[(k + 397) % 624] ^ (y >> 1) ^ ((y & 1u) ? 0x9908b0dfu : 0u);
      }
      mti = 0;
    }
    u32 y = mt[mti++];
    y ^= y >> 11;
    y ^= (y << 7)  & 0x9d2c5680u;
    y ^= (y << 15) & 0xefc60000u;
    y ^= y >> 18;
    return y;
  }
  u32 interval(u32 mx) {
    if (mx == 0u) return 0u;
    u32 mask = mx;
    mask |= mask >> 1; mask |= mask >> 2; mask |= mask >> 4;
    mask |= mask >> 8; mask |= mask >> 16;
    u32 v;
    while ((v = (next() & mask)) > mx) {}
    return v;
  }
};

void build_plan(int l, Plan* out) {
  HostMT rng;
  rng.seed((u32)l);
  for (int i = 0; i < NB_; i++) {
    bool fixedv[NB_] = {};
    fixedv[0] = true; fixedv[NB_ - 1] = true;
    for (int j = i - 1; j <= i + 1; j++)
      if (j >= 0 && j < NB_) fixedv[j] = true;
    int rest[NB_]; int nr = 0;
    for (int j = 0; j < NB_; j++) if (!fixedv[j]) rest[nr++] = j;
    int perm[NB_];
    for (int tt = 0; tt < nr; tt++) perm[tt] = tt;
    for (int tt = nr - 1; tt >= 1; tt--) {
      int j = (int)rng.interval((u32)tt);
      int tmp = perm[tt]; perm[tt] = perm[j]; perm[j] = tmp;
    }
    bool sel[NB_];
    for (int j = 0; j < NB_; j++) sel[j] = fixedv[j];
    for (int c = 0; c < 3; c++) sel[rest[perm[c]]] = true;
    int cnt = 0;
    for (int j = 0; j < NB_; j++)
      if (sel[j]) out->idx[i][cnt++] = (unsigned char)j;
    out->cnt[i] = (unsigned char)cnt;
    for (int c2 = cnt; c2 < KC_; c2++) out->idx[i][c2] = 0;
  }
}
}  // namespace

// ---------- host orchestration ----------
extern "C" void kernel_launch(void* const* d_in, const int* in_sizes, int n_in,
                              void* d_out, int out_size, void* d_ws, size_t ws_size,
                              hipStream_t stream) {
  (void)in_sizes; (void)n_in; (void)out_size; (void)ws_size;

  const int*   tokens = (const int*)d_in[0];
  const float* embed  = (const float*)d_in[1];
  const float* ln1_s  = (const float*)d_in[2];
  const float* ln1_b  = (const float*)d_in[3];
  const float* wq     = (const float*)d_in[4];
  const float* wk     = (const float*)d_in[5];
  const float* wv     = (const float*)d_in[6];
  const float* wo     = (const float*)d_in[7];
  const float* ln2_s  = (const float*)d_in[8];
  const float* ln2_b  = (const float*)d_in[9];
  const float* w1     = (const float*)d_in[10];
  const float* b1     = (const float*)d_in[11];
  const float* w2     = (const float*)d_in[12];
  const float* b2     = (const float*)d_in[13];
  const float* lnf_s  = (const float*)d_in[14];
  const float* lnf_b  = (const float*)d_in[15];

  char* wp = (char*)d_ws;
  auto take = [&](size_t bytes) {
    void* p = (void*)wp;
    wp += (bytes + 255) & ~(size_t)255;
    return p;
  };

  const int Mrows = B_ * S_;
  u16* wqkvT = (u16*)take((size_t)L_ * 1536 * D_ * 2);   // [L][1536][512] (gamma1-scaled)
  u16* woT   = (u16*)take((size_t)L_ * D_ * D_ * 2);     // [L][512][512]
  u16* w1T   = (u16*)take((size_t)L_ * FF_ * D_ * 2);    // [L][2048][512] (gamma2-scaled)
  u16* w2T   = (u16*)take((size_t)L_ * D_ * FF_ * 2);    // [L][512][2048]
  u16* x     = (u16*)take((size_t)Mrows * D_ * 2);       // residual stream, bf16
  u16* h     = (u16*)take((size_t)Mrows * D_ * 2);       // attn output
  float* pstats = (float*)take((size_t)Mrows * 16 * 4);  // [8192][8][2] partial LN stats
  float* uvq = (float*)take((size_t)L_ * 1536 * 2 * 4);  // per-col (u,v) for qkv
  float* uv1 = (float*)take((size_t)L_ * 2048 * 2 * 4);  // per-col (u,v) for w1
  u16* big   = (u16*)take((size_t)Mrows * FF_ * 2);      // {qkv+vT} | g, time-shared
  u16* qkv   = big;                                      // [8192][1024] q|k
  u16* vT    = big + (size_t)Mrows * 1024;               // [512][8192]
  u16* g     = big;

  Plan plans[L_];
  for (int l = 0; l < L_; l++) build_plan(l, &plans[l]);

  const size_t qkvL = (size_t)1536 * D_;

  transpose_all<<<dim3(3072, 1, L_), dim3(32, 8), 0, stream>>>(
      wq, wk, wv, wo, w1, w2, ln1_s, ln2_s, wqkvT, woT, w1T, w2T);
  compute_uv<<<L_ * 56, 256, 0, stream>>>(
      wq, wk, wv, w1, ln1_b, ln2_b, wqkvT, w1T, uvq, uv1);
  embed_stats<<<Mrows, 128, 0, stream>>>(tokens, embed, x, pstats);

  for (int l = 0; l < L_; l++) {
    gemm_pipe<0, true, 128, 128, true, false><<<768, 256, 0, stream>>>(
        x, wqkvT + (size_t)l * qkvL, D_, 1024, 12, qkv, nullptr, nullptr, vT,
        uvq + (size_t)l * 1536 * 2, pstats, nullptr);
    attn_mfma<<<B_ * NB_ * H_, 256, 0, stream>>>(qkv, vT, tokens, h, plans[l]);
    gemm_pipe<1, false, 64, 128, false, true><<<512, 256, 0, stream>>>(
        h, woT + (size_t)l * D_ * D_, D_, D_, 4, x, nullptr, x, nullptr,
        nullptr, nullptr, pstats);
    gemm_pipe<2, false, 128, 128, true, false><<<1024, 256, 0, stream>>>(
        x, w1T + (size_t)l * FF_ * D_, D_, FF_, 16, g, b1 + l * FF_, nullptr, nullptr,
        uv1 + (size_t)l * 2048 * 2, pstats, nullptr);
    gemm_pipe<3, false, 64, 128, false, true><<<512, 256, 0, stream>>>(
        g, w2T + (size_t)l * D_ * FF_, FF_, D_, 4, x, b2 + l * D_, x, nullptr,
        nullptr, nullptr, pstats);
  }
  ln_final<<<Mrows, 128, 0, stream>>>(x, pstats, lnf_s, lnf_b, (float*)d_out);
}